// Round 2
// baseline (2150.937 us; speedup 1.0000x reference)
//
#include <hip/hip_runtime.h>
#include <hip/hip_bf16.h>

typedef __hip_bfloat16 bf16;

#define NN 100000   // nodes
#define NE 640000   // edges
#define HD 128      // hidden

// flags[a]: 1 if float-array a is stored as f32, 0 if bf16.
// a: 0=node_emb 1=type_emb 2=len_emb 3=lane_emb 4=W(+b) 5=adj_val
__device__ __forceinline__ float ldmix(const void* p, size_t i, int f32) {
    return f32 ? ((const float*)p)[i]
               : __bfloat162float(((const bf16*)p)[i]);
}

// Per-array dtype sniffing: real bf16 data here has |v| < 1 (exp <= 126).
// f32 bits misread as bf16 halves contain exponents >= 130 (|v| >= 8) with
// p ~ 0.5 per low-half word -> detection certain within ~100 elements.
__global__ __launch_bounds__(256) void detect_kernel(
        const void* node_emb, const void* type_emb, const void* len_emb,
        const void* lane_emb, const void* W, const void* adj_val,
        int* __restrict__ flags) {
    __shared__ int found;
    const int a = blockIdx.x;  // 0..5
    const unsigned short* p;
    int n;
    switch (a) {
        case 0: p = (const unsigned short*)node_emb; n = 100000 * 64; break;
        case 1: p = (const unsigned short*)type_emb; n = 20 * 32;     break;
        case 2: p = (const unsigned short*)len_emb;  n = 100 * 16;    break;
        case 3: p = (const unsigned short*)lane_emb; n = 10 * 16;     break;
        case 4: p = (const unsigned short*)W;        n = HD * HD;     break;
        default: p = (const unsigned short*)adj_val; n = NE;          break;
    }
    if (n > 16384) n = 16384;   // n ushorts is in-bounds under either dtype
    if (threadIdx.x == 0) found = 0;
    __syncthreads();
    int loc = 0;
    for (int i = threadIdx.x; i < n; i += 256) {
        int e = (p[i] >> 7) & 0xFF;
        if (e >= 130) loc = 1;
    }
    if (loc) atomicOr(&found, 1);
    __syncthreads();
    if (threadIdx.x == 0) flags[a] = found;
}

// x[i,:] = concat(lane[16], type[32], length[16], node[64]) -> f32
__global__ __launch_bounds__(256) void embed_kernel(const int* __restrict__ nodef,
        const int* __restrict__ typef, const int* __restrict__ lenf,
        const int* __restrict__ lanef,
        const void* __restrict__ node_emb, const void* __restrict__ type_emb,
        const void* __restrict__ len_emb, const void* __restrict__ lane_emb,
        const int* __restrict__ flags, float* __restrict__ x) {
    int idx = blockIdx.x * 256 + threadIdx.x;   // grid sized exactly NN*HD
    int i = idx >> 7;
    int c = idx & 127;
    float v;
    if (c < 16)      v = ldmix(lane_emb, (size_t)lanef[i] * 16 + c,        flags[3]);
    else if (c < 48) v = ldmix(type_emb, (size_t)typef[i] * 32 + (c - 16), flags[1]);
    else if (c < 64) v = ldmix(len_emb,  (size_t)lenf[i]  * 16 + (c - 48), flags[2]);
    else             v = ldmix(node_emb, (size_t)nodef[i] * 64 + (c - 64), flags[0]);
    x[idx] = v;
}

// support = x @ W. 32 rows/block, 256 threads, 4x4 register tile/thread.
// W staged (with dtype branch) in LDS in two 64-row chunks. LDS = 50 KB.
__global__ __launch_bounds__(256) void gemm_kernel(const float* __restrict__ x,
        const void* __restrict__ W, const int* __restrict__ flags,
        void* __restrict__ sup, int sup_isbf) {
    __shared__ float Wl[64][HD];     // 32 KB
    __shared__ float xsT[HD][36];    // 18 KB, pad 36 keeps float4 reads 16B-aligned
    const int tid = threadIdx.x;
    const int row0 = blockIdx.x * 32;
    const int wf32 = flags[4];

    for (int t = tid; t < 32 * HD; t += 256) {
        int r = t >> 7;
        int c = t & 127;
        xsT[c][r] = x[(size_t)(row0 + r) * HD + c];
    }

    const int cx = (tid & 31) * 4;
    const int ry = (tid >> 5) * 4;
    float acc[4][4] = {};

    for (int kc = 0; kc < 2; ++kc) {
        __syncthreads();   // kc=0: xsT ready; kc=1: prev Wl reads done
        for (int t = tid; t < 64 * HD; t += 256)
            Wl[t >> 7][t & 127] = ldmix(W, (size_t)kc * 64 * HD + t, wf32);
        __syncthreads();
#pragma unroll 8
        for (int k = 0; k < 64; ++k) {
            const float4 wv = *(const float4*)&Wl[k][cx];
            const float4 xv = *(const float4*)&xsT[kc * 64 + k][ry];
            const float xr[4] = {xv.x, xv.y, xv.z, xv.w};
            const float wc[4] = {wv.x, wv.y, wv.z, wv.w};
#pragma unroll
            for (int r = 0; r < 4; ++r)
#pragma unroll
                for (int c = 0; c < 4; ++c)
                    acc[r][c] += xr[r] * wc[c];
        }
    }

    if (!sup_isbf) {
        float* sp = (float*)sup;
#pragma unroll
        for (int r = 0; r < 4; ++r) {
            float4 st = {acc[r][0], acc[r][1], acc[r][2], acc[r][3]};
            *(float4*)&sp[(size_t)(row0 + ry + r) * HD + cx] = st;
        }
    } else {
        bf16* sp = (bf16*)sup;
#pragma unroll
        for (int r = 0; r < 4; ++r)
#pragma unroll
            for (int c = 0; c < 4; ++c)
                sp[(size_t)(row0 + ry + r) * HD + cx + c] = __float2bfloat16(acc[r][c]);
    }
}

// agg[dst] += support[src] * val ; one edge per 64 threads, 2 cols/thread.
__global__ __launch_bounds__(256) void scatter_kernel(const void* __restrict__ sup,
        int sup_isbf, const int* __restrict__ src, const int* __restrict__ dst,
        const void* __restrict__ val, const int* __restrict__ flags,
        float* __restrict__ agg) {
    unsigned idx = blockIdx.x * 256u + threadIdx.x;  // grid sized exactly NE*64
    int e = idx >> 6;
    int c = (idx & 63) * 2;
    int s = src[e];
    int d = dst[e];
    float v = ldmix(val, e, flags[5]);
    float s0, s1;
    if (!sup_isbf) {
        const float2 sv = *(const float2*)((const float*)sup + (size_t)s * HD + c);
        s0 = sv.x; s1 = sv.y;
    } else {
        const bf16* sp = (const bf16*)sup;
        s0 = __bfloat162float(sp[(size_t)s * HD + c]);
        s1 = __bfloat162float(sp[(size_t)s * HD + c + 1]);
    }
    atomicAdd(agg + (size_t)d * HD + c,     s0 * v);
    atomicAdd(agg + (size_t)d * HD + c + 1, s1 * v);
}

// x += b (in place); on the last layer also emit output in detected dtype.
__global__ __launch_bounds__(256) void bias_kernel(float* __restrict__ x,
        const void* __restrict__ b_, const int* __restrict__ flags,
        void* __restrict__ out, int write_out) {
    int idx = blockIdx.x * 256 + threadIdx.x;  // grid sized exactly NN*HD
    float v = x[idx] + ldmix(b_, idx & 127, flags[4]);
    x[idx] = v;
    if (write_out) {
        int of32 = flags[0] & flags[1] & flags[2] & flags[3] & flags[4] & flags[5];
        if (of32) ((float*)out)[idx] = v;
        else      ((bf16*)out)[idx] = __float2bfloat16(v);
    }
}

extern "C" void kernel_launch(void* const* d_in, const int* in_sizes, int n_in,
                              void* d_out, int out_size, void* d_ws, size_t ws_size,
                              hipStream_t stream) {
    const int*  nodef    = (const int*)d_in[0];
    const int*  typef    = (const int*)d_in[1];
    const int*  lenf     = (const int*)d_in[2];
    const int*  lanef    = (const int*)d_in[3];
    const int*  adj_src  = (const int*)d_in[4];
    const int*  adj_dst  = (const int*)d_in[5];
    const void* adj_val  = d_in[6];
    const void* node_emb = d_in[7];
    const void* type_emb = d_in[8];
    const void* len_emb  = d_in[9];
    const void* lane_emb = d_in[10];
    const void* W        = d_in[11];
    const void* b        = d_in[12];

    // ws layout: [flags: 256 B] [X: NN*HD f32] [SUP: f32 | bf16 | aliased to d_out]
    const size_t xbytes = (size_t)NN * HD * sizeof(float);
    int*   flags = (int*)d_ws;
    float* X     = (float*)((char*)d_ws + 256);
    const size_t base = 256 + xbytes;
    void* SUP;
    int sup_isbf;
    if (ws_size >= base + xbytes)          { SUP = (char*)d_ws + base; sup_isbf = 0; }
    else if (ws_size >= base + xbytes / 2) { SUP = (char*)d_ws + base; sup_isbf = 1; }
    else                                   { SUP = d_out;              sup_isbf = 1; } // d_out as scratch; overwritten by final bias

    detect_kernel<<<6, 256, 0, stream>>>(node_emb, type_emb, len_emb, lane_emb,
                                         W, adj_val, flags);
    embed_kernel<<<(NN * HD) / 256, 256, 0, stream>>>(nodef, typef, lenf, lanef,
            node_emb, type_emb, len_emb, lane_emb, flags, X);

    for (int l = 0; l < 3; ++l) {
        gemm_kernel<<<NN / 32, 256, 0, stream>>>(X, W, flags, SUP, sup_isbf);
        hipMemsetAsync(X, 0, xbytes, stream);
        scatter_kernel<<<(NE * 64) / 256, 256, 0, stream>>>(SUP, sup_isbf,
                adj_src, adj_dst, adj_val, flags, X);
        bias_kernel<<<(NN * HD) / 256, 256, 0, stream>>>(X, b, flags, d_out, l == 2);
    }
}

// Round 3
// 999.136 us; speedup vs baseline: 2.1528x; 2.1528x over previous
//
#include <hip/hip_runtime.h>
#include <hip/hip_bf16.h>

typedef __hip_bfloat16 bf16;

#define NN 100000   // nodes
#define NE 640000   // edges
#define HD 128      // hidden

// flags[a]: 1 if float-array a is stored as f32, 0 if bf16.
// a: 0=node_emb 1=type_emb 2=len_emb 3=lane_emb 4=W(+b) 5=adj_val
__device__ __forceinline__ float ldmix(const void* p, size_t i, int f32) {
    return f32 ? ((const float*)p)[i]
               : __bfloat162float(((const bf16*)p)[i]);
}

// Per-array dtype sniffing: real bf16 data here has |v| < 1 (exp <= 126).
// f32 bits misread as bf16 halves contain exponents >= 130 with p ~ 0.5
// per low-half word -> detection certain within ~100 elements.
__global__ __launch_bounds__(256) void detect_kernel(
        const void* node_emb, const void* type_emb, const void* len_emb,
        const void* lane_emb, const void* W, const void* adj_val,
        int* __restrict__ flags) {
    __shared__ int found;
    const int a = blockIdx.x;  // 0..5
    const unsigned short* p;
    int n;
    switch (a) {
        case 0: p = (const unsigned short*)node_emb; n = 100000 * 64; break;
        case 1: p = (const unsigned short*)type_emb; n = 20 * 32;     break;
        case 2: p = (const unsigned short*)len_emb;  n = 100 * 16;    break;
        case 3: p = (const unsigned short*)lane_emb; n = 10 * 16;     break;
        case 4: p = (const unsigned short*)W;        n = HD * HD;     break;
        default: p = (const unsigned short*)adj_val; n = NE;          break;
    }
    if (n > 16384) n = 16384;   // n ushorts in-bounds under either dtype
    if (threadIdx.x == 0) found = 0;
    __syncthreads();
    int loc = 0;
    for (int i = threadIdx.x; i < n; i += 256) {
        int e = (p[i] >> 7) & 0xFF;
        if (e >= 130) loc = 1;
    }
    if (loc) atomicOr(&found, 1);
    __syncthreads();
    if (threadIdx.x == 0) flags[a] = found;
}

// x[i,:] = concat(lane[16], type[32], length[16], node[64]) -> f32
__global__ __launch_bounds__(256) void embed_kernel(const int* __restrict__ nodef,
        const int* __restrict__ typef, const int* __restrict__ lenf,
        const int* __restrict__ lanef,
        const void* __restrict__ node_emb, const void* __restrict__ type_emb,
        const void* __restrict__ len_emb, const void* __restrict__ lane_emb,
        const int* __restrict__ flags, float* __restrict__ x) {
    int idx = blockIdx.x * 256 + threadIdx.x;   // grid sized exactly NN*HD
    int i = idx >> 7;
    int c = idx & 127;
    float v;
    if (c < 16)      v = ldmix(lane_emb, (size_t)lanef[i] * 16 + c,        flags[3]);
    else if (c < 48) v = ldmix(type_emb, (size_t)typef[i] * 32 + (c - 16), flags[1]);
    else if (c < 64) v = ldmix(len_emb,  (size_t)lenf[i]  * 16 + (c - 48), flags[2]);
    else             v = ldmix(node_emb, (size_t)nodef[i] * 64 + (c - 64), flags[0]);
    x[idx] = v;
}

// ---- CSR build (once per call; dst-sorted edge list kills scatter atomics) ----

// cnt[dst]++ per edge
__global__ __launch_bounds__(256) void hist_kernel(const int* __restrict__ dst,
                                                   int* __restrict__ cnt) {
    int e = blockIdx.x * 256 + threadIdx.x;   // grid exactly NE
    atomicAdd(&cnt[dst[e]], 1);
}

// exclusive scan of cnt[NN] -> offs[NN+1], and pos = offs (running cursors)
__global__ __launch_bounds__(1024) void scan_kernel(const int* __restrict__ cnt,
        int* __restrict__ offs, int* __restrict__ pos) {
    __shared__ int part[1024];
    const int t = threadIdx.x;
    const int CH = (NN + 1023) / 1024;   // 98
    int lo = t * CH; if (lo > NN) lo = NN;
    int hi = lo + CH; if (hi > NN) hi = NN;
    int s = 0;
    for (int i = lo; i < hi; ++i) s += cnt[i];
    part[t] = s;
    __syncthreads();
    for (int off = 1; off < 1024; off <<= 1) {
        int v = 0;
        if (t >= off) v = part[t - off];
        __syncthreads();
        if (t >= off) part[t] += v;
        __syncthreads();
    }
    int run = (t == 0) ? 0 : part[t - 1];
    for (int i = lo; i < hi; ++i) {
        int d = cnt[i];
        offs[i] = run;
        pos[i] = run;
        run += d;
    }
    if (t == 1023) offs[NN] = run;   // == NE
}

// slot = pos[dst[e]]++ ; esrc[slot]=src[e]; eval[slot]=val[e] (as f32)
__global__ __launch_bounds__(256) void position_kernel(const int* __restrict__ src,
        const int* __restrict__ dst, const void* __restrict__ val,
        const int* __restrict__ flags, int* __restrict__ pos,
        int* __restrict__ esrc, float* __restrict__ eval) {
    int e = blockIdx.x * 256 + threadIdx.x;   // grid exactly NE
    int d = dst[e];
    int slot = atomicAdd(&pos[d], 1);
    esrc[slot] = src[e];
    eval[slot] = ldmix(val, e, flags[5]);
}

// ---- per-layer kernels ----

// support = x @ W. 32 rows/block, 256 threads, 4x4 register tile/thread.
__global__ __launch_bounds__(256) void gemm_kernel(const float* __restrict__ x,
        const void* __restrict__ W, const int* __restrict__ flags,
        void* __restrict__ sup, int sup_isbf) {
    __shared__ float Wl[64][HD];     // 32 KB
    __shared__ float xsT[HD][36];    // 18 KB
    const int tid = threadIdx.x;
    const int row0 = blockIdx.x * 32;
    const int wf32 = flags[4];

    for (int t = tid; t < 32 * HD; t += 256) {
        int r = t >> 7;
        int c = t & 127;
        xsT[c][r] = x[(size_t)(row0 + r) * HD + c];
    }

    const int cx = (tid & 31) * 4;
    const int ry = (tid >> 5) * 4;
    float acc[4][4] = {};

    for (int kc = 0; kc < 2; ++kc) {
        __syncthreads();
        for (int t = tid; t < 64 * HD; t += 256)
            Wl[t >> 7][t & 127] = ldmix(W, (size_t)kc * 64 * HD + t, wf32);
        __syncthreads();
#pragma unroll 8
        for (int k = 0; k < 64; ++k) {
            const float4 wv = *(const float4*)&Wl[k][cx];
            const float4 xv = *(const float4*)&xsT[kc * 64 + k][ry];
            const float xr[4] = {xv.x, xv.y, xv.z, xv.w};
            const float wc[4] = {wv.x, wv.y, wv.z, wv.w};
#pragma unroll
            for (int r = 0; r < 4; ++r)
#pragma unroll
                for (int c = 0; c < 4; ++c)
                    acc[r][c] += xr[r] * wc[c];
        }
    }

    if (!sup_isbf) {
        float* sp = (float*)sup;
#pragma unroll
        for (int r = 0; r < 4; ++r) {
            float4 st = {acc[r][0], acc[r][1], acc[r][2], acc[r][3]};
            *(float4*)&sp[(size_t)(row0 + ry + r) * HD + cx] = st;
        }
    } else {
        bf16* sp = (bf16*)sup;
#pragma unroll
        for (int r = 0; r < 4; ++r)
#pragma unroll
            for (int c = 0; c < 4; ++c)
                sp[(size_t)(row0 + ry + r) * HD + cx + c] = __float2bfloat16(acc[r][c]);
    }
}

// Pull-mode aggregation: one wave per dst node.
// X[d,:] = b + sum_j eval[j] * SUP[esrc[j],:]; optional bf16/f32 out write.
__global__ __launch_bounds__(256) void agg_kernel(const void* __restrict__ sup,
        int sup_isbf, const int* __restrict__ offs, const int* __restrict__ esrc,
        const float* __restrict__ eval, const void* __restrict__ b_,
        const int* __restrict__ flags, float* __restrict__ X,
        void* __restrict__ out, int write_out) {
    const int node = blockIdx.x * 4 + (threadIdx.x >> 6);   // grid exactly NN/4
    const int lane = threadIdx.x & 63;
    const int c = lane * 2;
    const int lo = offs[node];
    const int hi = offs[node + 1];
    float2 acc = {0.f, 0.f};
    if (!sup_isbf) {
        const float* sp = (const float*)sup;
        for (int j = lo; j < hi; ++j) {
            const int s = esrc[j];
            const float v = eval[j];
            const float2 sv = *(const float2*)(sp + (size_t)s * HD + c);
            acc.x += sv.x * v;
            acc.y += sv.y * v;
        }
    } else {
        const bf16* sp = (const bf16*)sup;
        for (int j = lo; j < hi; ++j) {
            const int s = esrc[j];
            const float v = eval[j];
            acc.x += __bfloat162float(sp[(size_t)s * HD + c]) * v;
            acc.y += __bfloat162float(sp[(size_t)s * HD + c + 1]) * v;
        }
    }
    acc.x += ldmix(b_, c, flags[4]);
    acc.y += ldmix(b_, c + 1, flags[4]);
    const size_t o = (size_t)node * HD + c;
    *(float2*)(X + o) = acc;
    if (write_out) {
        int of32 = flags[0] & flags[1] & flags[2] & flags[3] & flags[4] & flags[5];
        if (of32) {
            *(float2*)((float*)out + o) = acc;
        } else {
            ((bf16*)out)[o]     = __float2bfloat16(acc.x);
            ((bf16*)out)[o + 1] = __float2bfloat16(acc.y);
        }
    }
}

// fallback tier only (SUP aliased to d_out): final X -> out cast
__global__ __launch_bounds__(256) void cast_kernel(const float* __restrict__ X,
        const int* __restrict__ flags, void* __restrict__ out) {
    int idx = blockIdx.x * 256 + threadIdx.x;   // grid exactly NN*HD
    int of32 = flags[0] & flags[1] & flags[2] & flags[3] & flags[4] & flags[5];
    float v = X[idx];
    if (of32) ((float*)out)[idx] = v;
    else      ((bf16*)out)[idx] = __float2bfloat16(v);
}

extern "C" void kernel_launch(void* const* d_in, const int* in_sizes, int n_in,
                              void* d_out, int out_size, void* d_ws, size_t ws_size,
                              hipStream_t stream) {
    const int*  nodef    = (const int*)d_in[0];
    const int*  typef    = (const int*)d_in[1];
    const int*  lenf     = (const int*)d_in[2];
    const int*  lanef    = (const int*)d_in[3];
    const int*  adj_src  = (const int*)d_in[4];
    const int*  adj_dst  = (const int*)d_in[5];
    const void* adj_val  = d_in[6];
    const void* node_emb = d_in[7];
    const void* type_emb = d_in[8];
    const void* len_emb  = d_in[9];
    const void* lane_emb = d_in[10];
    const void* W        = d_in[11];
    const void* b        = d_in[12];

    // ws layout: flags(256B) | X f32 | cnt | offs | pos | esrc | eval | SUP
    const size_t xbytes = (size_t)NN * HD * sizeof(float);   // 51.2 MB
    char* wp = (char*)d_ws;
    int*   flags = (int*)wp;            wp += 256;
    float* X     = (float*)wp;          wp += xbytes;
    int*   cnt   = (int*)wp;            wp += (size_t)NN * 4;
    int*   offs  = (int*)wp;            wp += (size_t)(NN + 1) * 4 + 4; // keep 8-align
    int*   pos   = (int*)wp;            wp += (size_t)NN * 4;
    int*   esrc  = (int*)wp;            wp += (size_t)NE * 4;
    float* eval  = (float*)wp;          wp += (size_t)NE * 4;
    const size_t used = (size_t)(wp - (char*)d_ws);

    void* SUP;
    int sup_isbf, sup_is_out;
    if (ws_size >= used + xbytes)          { SUP = wp;    sup_isbf = 0; sup_is_out = 0; }
    else if (ws_size >= used + xbytes / 2) { SUP = wp;    sup_isbf = 1; sup_is_out = 0; }
    else                                   { SUP = d_out; sup_isbf = 1; sup_is_out = 1; }

    detect_kernel<<<6, 256, 0, stream>>>(node_emb, type_emb, len_emb, lane_emb,
                                         W, adj_val, flags);
    embed_kernel<<<(NN * HD) / 256, 256, 0, stream>>>(nodef, typef, lenf, lanef,
            node_emb, type_emb, len_emb, lane_emb, flags, X);

    // CSR build (graph identical across layers)
    hipMemsetAsync(cnt, 0, (size_t)NN * 4, stream);
    hist_kernel<<<NE / 256, 256, 0, stream>>>(adj_dst, cnt);
    scan_kernel<<<1, 1024, 0, stream>>>(cnt, offs, pos);
    position_kernel<<<NE / 256, 256, 0, stream>>>(adj_src, adj_dst, adj_val,
                                                  flags, pos, esrc, eval);

    for (int l = 0; l < 3; ++l) {
        gemm_kernel<<<NN / 32, 256, 0, stream>>>(X, W, flags, SUP, sup_isbf);
        const int wout = (l == 2 && !sup_is_out) ? 1 : 0;
        agg_kernel<<<NN / 4, 256, 0, stream>>>(SUP, sup_isbf, offs, esrc, eval,
                                               b, flags, X, d_out, wout);
    }
    if (sup_is_out)
        cast_kernel<<<(NN * HD) / 256, 256, 0, stream>>>(X, flags, d_out);
}

// Round 4
// 545.389 us; speedup vs baseline: 3.9439x; 1.8320x over previous
//
#include <hip/hip_runtime.h>
#include <hip/hip_bf16.h>

typedef __hip_bfloat16 bf16;
typedef unsigned short ushort_t;
typedef __attribute__((ext_vector_type(8))) short short8;
typedef __attribute__((ext_vector_type(4))) float f32x4;

#define NN 100000   // nodes
#define NE 640000   // edges
#define HD 128      // hidden
#define NB ((NN + 255) / 256)   // 391 scan blocks
#define LDA 136     // padded LDS row (bf16 elems): 68 words -> 2-way bank aliasing (free)

// flags[a]: 1 if float-array a is stored as f32, 0 if bf16.
// a: 0=node_emb 1=type_emb 2=len_emb 3=lane_emb 4=W(+b) 5=adj_val
__device__ __forceinline__ float ldmix(const void* p, size_t i, int f32) {
    return f32 ? ((const float*)p)[i]
               : __bfloat162float(((const bf16*)p)[i]);
}

// Per-array dtype sniffing: real bf16 data here has |v| < 1 (exp <= 126).
// f32 bits misread as bf16 halves have exponent >= 130 with p ~ 0.5/word.
__global__ __launch_bounds__(256) void detect_kernel(
        const void* node_emb, const void* type_emb, const void* len_emb,
        const void* lane_emb, const void* W, const void* adj_val,
        int* __restrict__ flags) {
    __shared__ int found;
    const int a = blockIdx.x;  // 0..5
    const unsigned short* p;
    int n;
    switch (a) {
        case 0: p = (const unsigned short*)node_emb; n = 100000 * 64; break;
        case 1: p = (const unsigned short*)type_emb; n = 20 * 32;     break;
        case 2: p = (const unsigned short*)len_emb;  n = 100 * 16;    break;
        case 3: p = (const unsigned short*)lane_emb; n = 10 * 16;     break;
        case 4: p = (const unsigned short*)W;        n = HD * HD;     break;
        default: p = (const unsigned short*)adj_val; n = NE;          break;
    }
    if (n > 16384) n = 16384;
    if (threadIdx.x == 0) found = 0;
    __syncthreads();
    int loc = 0;
    for (int i = threadIdx.x; i < n; i += 256) {
        int e = (p[i] >> 7) & 0xFF;
        if (e >= 130) loc = 1;
    }
    if (loc) atomicOr(&found, 1);
    __syncthreads();
    if (threadIdx.x == 0) flags[a] = found;
}

// x[i,:] = concat(lane[16], type[32], length[16], node[64]) -> f32
__global__ __launch_bounds__(256) void embed_kernel(const int* __restrict__ nodef,
        const int* __restrict__ typef, const int* __restrict__ lenf,
        const int* __restrict__ lanef,
        const void* __restrict__ node_emb, const void* __restrict__ type_emb,
        const void* __restrict__ len_emb, const void* __restrict__ lane_emb,
        const int* __restrict__ flags, float* __restrict__ x) {
    int idx = blockIdx.x * 256 + threadIdx.x;   // grid exactly NN*HD
    int i = idx >> 7;
    int c = idx & 127;
    float v;
    if (c < 16)      v = ldmix(lane_emb, (size_t)lanef[i] * 16 + c,        flags[3]);
    else if (c < 48) v = ldmix(type_emb, (size_t)typef[i] * 32 + (c - 16), flags[1]);
    else if (c < 64) v = ldmix(len_emb,  (size_t)lenf[i]  * 16 + (c - 48), flags[2]);
    else             v = ldmix(node_emb, (size_t)nodef[i] * 64 + (c - 64), flags[0]);
    x[idx] = v;
}

// ---- CSR build ----

__global__ __launch_bounds__(256) void hist_kernel(const int* __restrict__ dst,
                                                   int* __restrict__ cnt) {
    int e = blockIdx.x * 256 + threadIdx.x;   // grid exactly NE
    atomicAdd(&cnt[dst[e]], 1);
}

// phase 1: per-block sums of cnt
__global__ __launch_bounds__(256) void scan1_kernel(const int* __restrict__ cnt,
                                                    int* __restrict__ bsum) {
    int idx = blockIdx.x * 256 + threadIdx.x;
    int v = (idx < NN) ? cnt[idx] : 0;
    for (int o = 32; o; o >>= 1) v += __shfl_down(v, o, 64);
    __shared__ int ws_[4];
    if ((threadIdx.x & 63) == 0) ws_[threadIdx.x >> 6] = v;
    __syncthreads();
    if (threadIdx.x == 0) bsum[blockIdx.x] = ws_[0] + ws_[1] + ws_[2] + ws_[3];
}

// phase 2: exclusive scan of the NB block sums (single small block)
__global__ __launch_bounds__(512) void scan2_kernel(const int* __restrict__ bsum,
                                                    int* __restrict__ boff) {
    __shared__ int s[512];
    int t = threadIdx.x;
    int v = (t < NB) ? bsum[t] : 0;
    s[t] = v;
    __syncthreads();
    for (int o = 1; o < 512; o <<= 1) {
        int u = (t >= o) ? s[t - o] : 0;
        __syncthreads();
        s[t] += u;
        __syncthreads();
    }
    if (t < NB) boff[t] = s[t] - v;
}

// phase 3: per-block local exclusive scan + block offset -> offs, pos
__global__ __launch_bounds__(256) void scan3_kernel(const int* __restrict__ cnt,
        const int* __restrict__ boff, int* __restrict__ offs, int* __restrict__ pos) {
    __shared__ int s[256];
    int idx = blockIdx.x * 256 + threadIdx.x;
    int t = threadIdx.x;
    int v = (idx < NN) ? cnt[idx] : 0;
    s[t] = v;
    __syncthreads();
    for (int o = 1; o < 256; o <<= 1) {
        int u = (t >= o) ? s[t - o] : 0;
        __syncthreads();
        s[t] += u;
        __syncthreads();
    }
    int excl = s[t] - v + boff[blockIdx.x];
    if (idx <= NN) {
        offs[idx] = excl;           // idx==NN gets total == NE
        if (idx < NN) pos[idx] = excl;
    }
}

// slot = pos[dst[e]]++ ; esrc[slot]=src[e]; eval[slot]=val[e] (as f32)
__global__ __launch_bounds__(256) void position_kernel(const int* __restrict__ src,
        const int* __restrict__ dst, const void* __restrict__ val,
        const int* __restrict__ flags, int* __restrict__ pos,
        int* __restrict__ esrc, float* __restrict__ eval) {
    int e = blockIdx.x * 256 + threadIdx.x;   // grid exactly NE
    int d = dst[e];
    int slot = atomicAdd(&pos[d], 1);
    esrc[slot] = src[e];
    eval[slot] = ldmix(val, e, flags[5]);
}

// W -> Wt[n][k] bf16 (pre-transposed so MFMA B-frags are contiguous ds_read_b128)
__global__ __launch_bounds__(256) void prep_kernel(const void* __restrict__ W,
        const int* __restrict__ flags, ushort_t* __restrict__ Wt) {
    int idx = blockIdx.x * 256 + threadIdx.x;   // grid 64 -> 16384
    int n = idx >> 7;
    int k = idx & 127;
    float v = ldmix(W, (size_t)k * HD + n, flags[4]);
    bf16 h = __float2bfloat16(v);
    Wt[idx] = *(ushort_t*)&h;
}

// ---- per-layer kernels ----

// SUP = X @ W via mfma_f32_16x16x32_bf16. Block: 256 thr = 4 waves, 64 rows.
// Wave w computes cols [w*32, w*32+32) for all 64 rows.
// A-frag: A[m=lane&15][k=quad*8+j]; B-frag: B[k=quad*8+j][n=lane&15];
// C/D: col=lane&15, row=quad*4+reg  (m89/m118-verified layouts).
__global__ __launch_bounds__(256) void gemm_kernel(const float* __restrict__ X,
        const ushort_t* __restrict__ Wt, void* __restrict__ sup, int sup_isbf) {
    __shared__ ushort_t Xs[64 * LDA];    // 17.0 KB
    __shared__ ushort_t Ws[128 * LDA];   // 34.0 KB
    const int tid = threadIdx.x;
    const int row0 = blockIdx.x * 64;

    // stage X tile f32 -> bf16 (clamp tail rows)
#pragma unroll
    for (int i = 0; i < 8; ++i) {
        int chunk = i * 256 + tid;          // 0..2047
        int m = chunk >> 5;                 // 0..63
        int c4 = (chunk & 31) * 4;
        int gm = row0 + m;
        if (gm >= NN) gm = NN - 1;
        const float4 xv = *(const float4*)&X[(size_t)gm * HD + c4];
        bf16 h0 = __float2bfloat16(xv.x), h1 = __float2bfloat16(xv.y);
        bf16 h2 = __float2bfloat16(xv.z), h3 = __float2bfloat16(xv.w);
        ushort4 uv;
        uv.x = *(ushort_t*)&h0; uv.y = *(ushort_t*)&h1;
        uv.z = *(ushort_t*)&h2; uv.w = *(ushort_t*)&h3;
        *(ushort4*)&Xs[m * LDA + c4] = uv;
    }
    // stage Wt (bf16, straight copy into padded rows)
#pragma unroll
    for (int i = 0; i < 8; ++i) {
        int chunk = i * 256 + tid;          // 0..2047
        int n = chunk >> 4;
        int k8 = (chunk & 15) * 8;
        *(uint4*)&Ws[n * LDA + k8] = *(const uint4*)&Wt[n * HD + k8];
    }
    __syncthreads();

    const int w = tid >> 6;
    const int lane = tid & 63;
    const int ln = lane & 15;
    const int quad = lane >> 4;
    const int koff = quad * 8;

    short8 bfrg[2][4];
#pragma unroll
    for (int nt = 0; nt < 2; ++nt)
#pragma unroll
        for (int kc = 0; kc < 4; ++kc)
            bfrg[nt][kc] = *(const short8*)&Ws[(w * 32 + nt * 16 + ln) * LDA + kc * 32 + koff];

    f32x4 acc[4][2];
    const f32x4 zero = {0.f, 0.f, 0.f, 0.f};
#pragma unroll
    for (int mt = 0; mt < 4; ++mt) {
        acc[mt][0] = zero;
        acc[mt][1] = zero;
    }

#pragma unroll
    for (int mt = 0; mt < 4; ++mt) {
        short8 afrg[4];
#pragma unroll
        for (int kc = 0; kc < 4; ++kc)
            afrg[kc] = *(const short8*)&Xs[(mt * 16 + ln) * LDA + kc * 32 + koff];
#pragma unroll
        for (int nt = 0; nt < 2; ++nt)
#pragma unroll
            for (int kc = 0; kc < 4; ++kc)
                acc[mt][nt] = __builtin_amdgcn_mfma_f32_16x16x32_bf16(
                        afrg[kc], bfrg[nt][kc], acc[mt][nt], 0, 0, 0);
    }

    if (!sup_isbf) {
        float* sp = (float*)sup;
#pragma unroll
        for (int mt = 0; mt < 4; ++mt)
#pragma unroll
            for (int reg = 0; reg < 4; ++reg) {
                int gm = row0 + mt * 16 + quad * 4 + reg;
                if (gm < NN) {
#pragma unroll
                    for (int nt = 0; nt < 2; ++nt)
                        sp[(size_t)gm * HD + w * 32 + nt * 16 + ln] = acc[mt][nt][reg];
                }
            }
    } else {
        bf16* sp = (bf16*)sup;
#pragma unroll
        for (int mt = 0; mt < 4; ++mt)
#pragma unroll
            for (int reg = 0; reg < 4; ++reg) {
                int gm = row0 + mt * 16 + quad * 4 + reg;
                if (gm < NN) {
#pragma unroll
                    for (int nt = 0; nt < 2; ++nt)
                        sp[(size_t)gm * HD + w * 32 + nt * 16 + ln] =
                                __float2bfloat16(acc[mt][nt][reg]);
                }
            }
    }
}

// Pull-mode aggregation: one wave per dst node.
// X[d,:] = b + sum_j eval[j] * SUP[esrc[j],:]; optional out write.
__global__ __launch_bounds__(256) void agg_kernel(const void* __restrict__ sup,
        int sup_isbf, const int* __restrict__ offs, const int* __restrict__ esrc,
        const float* __restrict__ eval, const void* __restrict__ b_,
        const int* __restrict__ flags, float* __restrict__ X,
        void* __restrict__ out, int write_out) {
    const int node = blockIdx.x * 4 + (threadIdx.x >> 6);   // grid exactly NN/4
    const int lane = threadIdx.x & 63;
    const int c = lane * 2;
    const int lo = offs[node];
    const int hi = offs[node + 1];
    float2 acc = {0.f, 0.f};
    if (!sup_isbf) {
        const float* sp = (const float*)sup;
        for (int j = lo; j < hi; ++j) {
            const int s = esrc[j];
            const float v = eval[j];
            const float2 sv = *(const float2*)(sp + (size_t)s * HD + c);
            acc.x += sv.x * v;
            acc.y += sv.y * v;
        }
    } else {
        const bf16* sp = (const bf16*)sup;
        for (int j = lo; j < hi; ++j) {
            const int s = esrc[j];
            const float v = eval[j];
            acc.x += __bfloat162float(sp[(size_t)s * HD + c]) * v;
            acc.y += __bfloat162float(sp[(size_t)s * HD + c + 1]) * v;
        }
    }
    acc.x += ldmix(b_, c, flags[4]);
    acc.y += ldmix(b_, c + 1, flags[4]);
    const size_t o = (size_t)node * HD + c;
    *(float2*)(X + o) = acc;
    if (write_out) {
        int of32 = flags[0] & flags[1] & flags[2] & flags[3] & flags[4] & flags[5];
        if (of32) {
            *(float2*)((float*)out + o) = acc;
        } else {
            ((bf16*)out)[o]     = __float2bfloat16(acc.x);
            ((bf16*)out)[o + 1] = __float2bfloat16(acc.y);
        }
    }
}

// fallback tier only (SUP aliased to d_out): final X -> out cast
__global__ __launch_bounds__(256) void cast_kernel(const float* __restrict__ X,
        const int* __restrict__ flags, void* __restrict__ out) {
    int idx = blockIdx.x * 256 + threadIdx.x;   // grid exactly NN*HD
    int of32 = flags[0] & flags[1] & flags[2] & flags[3] & flags[4] & flags[5];
    float v = X[idx];
    if (of32) ((float*)out)[idx] = v;
    else      ((bf16*)out)[idx] = __float2bfloat16(v);
}

extern "C" void kernel_launch(void* const* d_in, const int* in_sizes, int n_in,
                              void* d_out, int out_size, void* d_ws, size_t ws_size,
                              hipStream_t stream) {
    const int*  nodef    = (const int*)d_in[0];
    const int*  typef    = (const int*)d_in[1];
    const int*  lenf     = (const int*)d_in[2];
    const int*  lanef    = (const int*)d_in[3];
    const int*  adj_src  = (const int*)d_in[4];
    const int*  adj_dst  = (const int*)d_in[5];
    const void* adj_val  = d_in[6];
    const void* node_emb = d_in[7];
    const void* type_emb = d_in[8];
    const void* len_emb  = d_in[9];
    const void* lane_emb = d_in[10];
    const void* W        = d_in[11];
    const void* b        = d_in[12];

    // ws layout (all chunk sizes multiples of 16 B)
    const size_t xbytes = (size_t)NN * HD * sizeof(float);   // 51.2 MB
    char* wp = (char*)d_ws;
    int*      flags = (int*)wp;      wp += 256;
    float*    X     = (float*)wp;    wp += xbytes;
    int*      cnt   = (int*)wp;      wp += (size_t)NN * 4;       // 400000
    int*      offs  = (int*)wp;      wp += 400016;               // NN+1 ints, padded
    int*      pos   = (int*)wp;      wp += (size_t)NN * 4;
    int*      esrc  = (int*)wp;      wp += (size_t)NE * 4;
    float*    eval  = (float*)wp;    wp += (size_t)NE * 4;
    ushort_t* Wt    = (ushort_t*)wp; wp += 32768;
    int*      bsum  = (int*)wp;      wp += 1600;
    int*      boff  = (int*)wp;      wp += 1600;
    const size_t used = (size_t)(wp - (char*)d_ws);

    void* SUP;
    int sup_isbf, sup_is_out;
    if (ws_size >= used + xbytes)          { SUP = wp;    sup_isbf = 0; sup_is_out = 0; }
    else if (ws_size >= used + xbytes / 2) { SUP = wp;    sup_isbf = 1; sup_is_out = 0; }
    else                                   { SUP = d_out; sup_isbf = 1; sup_is_out = 1; }

    detect_kernel<<<6, 256, 0, stream>>>(node_emb, type_emb, len_emb, lane_emb,
                                         W, adj_val, flags);
    embed_kernel<<<(NN * HD) / 256, 256, 0, stream>>>(nodef, typef, lenf, lanef,
            node_emb, type_emb, len_emb, lane_emb, flags, X);

    // CSR build (graph identical across layers)
    hipMemsetAsync(cnt, 0, (size_t)NN * 4, stream);
    hist_kernel<<<NE / 256, 256, 0, stream>>>(adj_dst, cnt);
    scan1_kernel<<<NB, 256, 0, stream>>>(cnt, bsum);
    scan2_kernel<<<1, 512, 0, stream>>>(bsum, boff);
    scan3_kernel<<<NB, 256, 0, stream>>>(cnt, boff, offs, pos);
    position_kernel<<<NE / 256, 256, 0, stream>>>(adj_src, adj_dst, adj_val,
                                                  flags, pos, esrc, eval);
    prep_kernel<<<64, 256, 0, stream>>>(W, flags, Wt);

    for (int l = 0; l < 3; ++l) {
        gemm_kernel<<<(NN + 63) / 64, 256, 0, stream>>>(X, Wt, SUP, sup_isbf);
        const int wout = (l == 2 && !sup_is_out) ? 1 : 0;
        agg_kernel<<<NN / 4, 256, 0, stream>>>(SUP, sup_isbf, offs, esrc, eval,
                                               b, flags, X, d_out, wout);
    }
    if (sup_is_out)
        cast_kernel<<<(NN * HD) / 256, 256, 0, stream>>>(X, flags, d_out);
}